// Round 3
// baseline (727.864 us; speedup 1.0000x reference)
//
#include <hip/hip_runtime.h>

// GraphAttention (e3nn-style) on MI355X — Round 2 (resubmit after GPU timeout):
// CSR two-phase, no output atomics.
// Dims: M0=16 M1=8 Q0=8 Q1=4 O0=16 O1=8 EDGE_BASIS=16 HIDDEN=32
//
// Pipeline:
//  node_pre    : per-node qd = (x@Wq)@wdot (folded); zero cnt[]; probe edge_index
//                layout (int32 vs int64).
//  count_edges : cnt[rcv]++ histogram.
//  scan_kernel : exclusive prefix sum -> start[N+1], cursor[N] (1 block).
//  edge_compute: full per-edge TP/attention math (same as round 1);
//                pos = atomicAdd(cursor[rcv],1)  (CSR slot, issued early);
//                writes exbuf[pos]=exp(dot), vbuf[pos][0..39]=exp(dot/2)*v.
//  node_reduce : 1 wave per node; sums contiguous CSR rows; out = sum * rsqrt(z).
//
// ws layout (4B units): qd[N*20] | cnt[N] | start[N+1] | cursor[N] | flag |
//                       (pad to 16B) | exbuf[E] | vbuf[E*40]

#define BS 64

__device__ __forceinline__ float silu_f(float x) {
    return x * (1.0f / (1.0f + __expf(-x)));
}

__global__ __launch_bounds__(256) void node_pre(
    const float* __restrict__ node_ft,
    const int*   __restrict__ ei,
    const float* __restrict__ w_q_s,   // [16,8]
    const float* __restrict__ w_q_v,   // [8,4]
    const float* __restrict__ wdot_s,  // [8,8]
    const float* __restrict__ wdot_v,  // [4,4]
    float* __restrict__ qd,            // [N,20]
    int*   __restrict__ cnt,           // [N]
    int*   __restrict__ flag,
    int N, int E)
{
    const int n = blockIdx.x * blockDim.x + threadIdx.x;
    if (n == 0) {
        // int64 layout => every odd 32-bit word (high half of value < N) is 0.
        int acc = 0;
        const int kmax = (E < 64) ? E : 64;
        for (int k = 0; k < kmax; ++k) acc |= ei[2*k + 1];
        *flag = (acc == 0) ? 1 : 0;
    }
    if (n >= N) return;
    cnt[n] = 0;

    const float* nf = node_ft + (size_t)n * 40;
    float xs[16];
#pragma unroll
    for (int i = 0; i < 16; ++i) xs[i] = nf[i];

    float q[8];
#pragma unroll
    for (int o = 0; o < 8; ++o) {
        float a = 0.f;
#pragma unroll
        for (int i = 0; i < 16; ++i) a += xs[i] * w_q_s[i*8 + o];
        q[o] = a * 0.25f;                       // 1/sqrt(16)
    }
    float* qdn = qd + (size_t)n * 20;
#pragma unroll
    for (int j = 0; j < 8; ++j) {
        float a = 0.f;
#pragma unroll
        for (int i = 0; i < 8; ++i) a += q[i] * wdot_s[i*8 + j];
        qdn[j] = a;
    }

    float xv[8][3];
#pragma unroll
    for (int i = 0; i < 8; ++i)
#pragma unroll
        for (int c = 0; c < 3; ++c) xv[i][c] = nf[16 + i*3 + c];

    float qv[4][3];
#pragma unroll
    for (int o = 0; o < 4; ++o)
#pragma unroll
        for (int c = 0; c < 3; ++c) {
            float a = 0.f;
#pragma unroll
            for (int i = 0; i < 8; ++i) a += xv[i][c] * w_q_v[i*4 + o];
            qv[o][c] = a * 0.35355339059327379f;  // 1/sqrt(8)
        }
#pragma unroll
    for (int j = 0; j < 4; ++j)
#pragma unroll
        for (int c = 0; c < 3; ++c) {
            float a = 0.f;
#pragma unroll
            for (int i = 0; i < 4; ++i) a += qv[i][c] * wdot_v[i*4 + j];
            qdn[8 + j*3 + c] = a;
        }
}

__global__ __launch_bounds__(256) void count_edges(
    const int* __restrict__ ei,
    int* __restrict__ cnt,
    const int* __restrict__ flag,
    int E)
{
    const int e = blockIdx.x * blockDim.x + threadIdx.x;
    if (e >= E) return;
    const int is64 = *flag;
    const int rcv = is64 ? ei[2*(E + e)] : ei[E + e];
    atomicAdd(cnt + rcv, 1);
}

__global__ __launch_bounds__(1024) void scan_kernel(
    const int* __restrict__ cnt,
    int* __restrict__ start,    // [N+1]
    int* __restrict__ cursor,   // [N]
    int N)
{
    __shared__ int buf[1024];
    __shared__ int s_carry;
    const int tid = threadIdx.x;
    if (tid == 0) s_carry = 0;
    __syncthreads();
    for (int base = 0; base < N; base += 1024) {
        const int i = base + tid;
        const int v = (i < N) ? cnt[i] : 0;
        buf[tid] = v;
        __syncthreads();
#pragma unroll
        for (int off = 1; off < 1024; off <<= 1) {
            const int t = (tid >= off) ? buf[tid - off] : 0;
            __syncthreads();
            buf[tid] += t;
            __syncthreads();
        }
        const int carry = s_carry;
        if (i < N) {
            const int s = carry + buf[tid] - v;   // exclusive
            start[i] = s;
            cursor[i] = s;
        }
        __syncthreads();
        if (tid == 0) s_carry = carry + buf[1023];
        __syncthreads();
    }
    if (tid == 0) start[N] = s_carry;
}

__global__ __launch_bounds__(BS) void edge_compute(
    const float* __restrict__ node_ft,
    const int*   __restrict__ ei,
    const float* __restrict__ edge_sh,      // [E,4]
    const float* __restrict__ edge_scalars, // [E,16]
    const float* __restrict__ fck_w1,       // [16,32]
    const float* __restrict__ fck_w2,       // [32,320]
    const float* __restrict__ fcv_w1,       // [16,32]
    const float* __restrict__ fcv_w2,       // [32,640]
    const float* __restrict__ qd,           // [N,20]
    int*   __restrict__ cursor,             // [N] CSR write cursors
    float* __restrict__ exbuf,              // [E]
    float* __restrict__ vbuf,               // [E,40]
    const int* __restrict__ flag,
    int N, int E)
{
    // LDS = dynamically-indexable private storage (lane-consecutive columns,
    // conflict-free); h stays in VGPRs (j loops fully unrolled).
    __shared__ float s_xs[16][BS];
    __shared__ float s_xv[3][8][BS];
    __shared__ float s_pvv[8][BS];

    const int tid = threadIdx.x;
    const int e = blockIdx.x * BS + tid;
    if (e >= E) return;

    const int is64 = *flag;
    const int snd = is64 ? ei[2*e]       : ei[e];
    const int rcv = is64 ? ei[2*(E + e)] : ei[E + e];

    // CSR slot — issue the returning atomic EARLY so its latency hides under
    // the ~32k FMAs below.
    const int pos = atomicAdd(cursor + rcv, 1);

    const float4 sh4 = *(const float4*)(edge_sh + (size_t)e * 4);
    const float shs = sh4.x;
    const float shv_[3] = {sh4.y, sh4.z, sh4.w};

    // gather sender features -> LDS
    {
        const float4* nf4 = (const float4*)(node_ft + (size_t)snd * 40);
        float xb[40];
#pragma unroll
        for (int t = 0; t < 10; ++t) {
            const float4 v = nf4[t];
            xb[4*t+0] = v.x; xb[4*t+1] = v.y; xb[4*t+2] = v.z; xb[4*t+3] = v.w;
        }
#pragma unroll
        for (int i = 0; i < 16; ++i) s_xs[i][tid] = xb[i];
#pragma unroll
        for (int i = 0; i < 8; ++i) {
            const float a = xb[16 + i*3 + 0];
            const float b = xb[16 + i*3 + 1];
            const float c = xb[16 + i*3 + 2];
            s_xv[0][i][tid] = a; s_xv[1][i][tid] = b; s_xv[2][i][tid] = c;
            s_pvv[i][tid] = (a*shv_[0] + b*shv_[1] + c*shv_[2]) * 0.57735026918962576f;
        }
    }

    float es[16];
    {
        const float4* esp = (const float4*)(edge_scalars + (size_t)e * 16);
#pragma unroll
        for (int t = 0; t < 4; ++t) {
            const float4 v = esp[t];
            es[4*t+0] = v.x; es[4*t+1] = v.y; es[4*t+2] = v.z; es[4*t+3] = v.w;
        }
    }

    // ================= K side =================
    float hk[32];
#pragma unroll
    for (int j = 0; j < 32; ++j) {
        float a = 0.f;
#pragma unroll
        for (int t = 0; t < 16; ++t) a += es[t] * fck_w1[t*32 + j];
        hk[j] = silu_f(a * 0.25f);
    }

    float tk1[8] = {}, tk3[4] = {};
#pragma unroll 1
    for (int i = 0; i < 16; ++i) {
        float w1[8] = {}, w3[4] = {};
#pragma unroll
        for (int j = 0; j < 32; ++j) {
            const float hj = hk[j];
            const float* Wr = fck_w2 + j*320;
#pragma unroll
            for (int o = 0; o < 8; ++o) w1[o] += hj * Wr[i*8 + o];
#pragma unroll
            for (int o = 0; o < 4; ++o) w3[o] += hj * Wr[192 + i*4 + o];
        }
        const float p = s_xs[i][tid];
#pragma unroll
        for (int o = 0; o < 8; ++o) tk1[o] += p * w1[o];
#pragma unroll
        for (int o = 0; o < 4; ++o) tk3[o] += p * w3[o];
    }

    float tk2[8] = {};
#pragma unroll 1
    for (int i = 0; i < 8; ++i) {
        float w2[8] = {};
#pragma unroll
        for (int j = 0; j < 32; ++j) {
            const float hj = hk[j];
            const float* Wr = fck_w2 + j*320;
#pragma unroll
            for (int o = 0; o < 8; ++o) w2[o] += hj * Wr[128 + i*8 + o];
        }
        const float p = s_pvv[i][tid];
#pragma unroll
        for (int o = 0; o < 8; ++o) tk2[o] += p * w2[o];
    }

    float tk4[4][3] = {}, tk5[4][3] = {};
#pragma unroll 1
    for (int i = 0; i < 8; ++i) {
        float w4[4] = {}, w5[4] = {};
#pragma unroll
        for (int j = 0; j < 32; ++j) {
            const float hj = hk[j];
            const float* Wr = fck_w2 + j*320;
#pragma unroll
            for (int o = 0; o < 4; ++o) w4[o] += hj * Wr[256 + i*4 + o];
#pragma unroll
            for (int o = 0; o < 4; ++o) w5[o] += hj * Wr[288 + i*4 + o];
        }
        const float x0 = s_xv[0][i][tid];
        const float x1 = s_xv[1][i][tid];
        const float x2 = s_xv[2][i][tid];
#pragma unroll
        for (int o = 0; o < 4; ++o) {
            tk4[o][0] += x0*w4[o]; tk4[o][1] += x1*w4[o]; tk4[o][2] += x2*w4[o];
            tk5[o][0] += x0*w5[o]; tk5[o][1] += x1*w5[o]; tk5[o][2] += x2*w5[o];
        }
    }

    // dot with qd[recv]; scales folded:
    //  CS = 1/sqrt(32)/sqrt(24)/sqrt(80), CV = (1/32)*(1/sqrt3)/sqrt(80)
    float qdr[20];
    {
        const float4* qp = (const float4*)(qd + (size_t)rcv * 20);
#pragma unroll
        for (int t = 0; t < 5; ++t) {
            const float4 v = qp[t];
            qdr[4*t+0] = v.x; qdr[4*t+1] = v.y; qdr[4*t+2] = v.z; qdr[4*t+3] = v.w;
        }
    }
    float dots = 0.f, dotv = 0.f;
#pragma unroll
    for (int o = 0; o < 8; ++o) dots += qdr[o] * (shs*tk1[o] + tk2[o]);
#pragma unroll
    for (int o = 0; o < 4; ++o)
#pragma unroll
        for (int c = 0; c < 3; ++c) {
            const int c1 = (c+1) % 3, c2 = (c+2) % 3;
            const float kv = tk3[o]*shv_[c] + shs*tk4[o][c]
                + (shv_[c2]*tk5[o][c1] - shv_[c1]*tk5[o][c2]) * 0.70710678118654752f;
            dotv += qdr[8 + o*3 + c] * kv;
        }
    const float dot = dots * 4.0343567508008e-3f + dotv * 2.0171788261497e-3f;

    const float sa = __expf(0.5f * dot);   // sqrt(exp(dot))
    const float ex = sa * sa;              // exp(dot)

    // ================= V side =================
    float hv[32];
#pragma unroll
    for (int j = 0; j < 32; ++j) {
        float a = 0.f;
#pragma unroll
        for (int t = 0; t < 16; ++t) a += es[t] * fcv_w1[t*32 + j];
        hv[j] = silu_f(a * 0.25f);
    }

    float tv1[16] = {}, tv3[8] = {};
#pragma unroll 1
    for (int i = 0; i < 16; ++i) {
        float w1[16] = {}, w3[8] = {};
#pragma unroll
        for (int j = 0; j < 32; ++j) {
            const float hj = hv[j];
            const float* Wr = fcv_w2 + j*640;
#pragma unroll
            for (int o = 0; o < 16; ++o) w1[o] += hj * Wr[i*16 + o];
#pragma unroll
            for (int o = 0; o < 8; ++o)  w3[o] += hj * Wr[384 + i*8 + o];
        }
        const float p = s_xs[i][tid];
#pragma unroll
        for (int o = 0; o < 16; ++o) tv1[o] += p * w1[o];
#pragma unroll
        for (int o = 0; o < 8; ++o)  tv3[o] += p * w3[o];
    }

    float tv2[16] = {};
#pragma unroll 1
    for (int i = 0; i < 8; ++i) {
        float w2[16] = {};
#pragma unroll
        for (int j = 0; j < 32; ++j) {
            const float hj = hv[j];
            const float* Wr = fcv_w2 + j*640;
#pragma unroll
            for (int o = 0; o < 16; ++o) w2[o] += hj * Wr[256 + i*16 + o];
        }
        const float p = s_pvv[i][tid];
#pragma unroll
        for (int o = 0; o < 16; ++o) tv2[o] += p * w2[o];
    }

    float tv4[8][3] = {}, tv5[8][3] = {};
#pragma unroll 1
    for (int i = 0; i < 8; ++i) {
        float w4[8] = {}, w5[8] = {};
#pragma unroll
        for (int j = 0; j < 32; ++j) {
            const float hj = hv[j];
            const float* Wr = fcv_w2 + j*640;
#pragma unroll
            for (int o = 0; o < 8; ++o) w4[o] += hj * Wr[512 + i*8 + o];
#pragma unroll
            for (int o = 0; o < 8; ++o) w5[o] += hj * Wr[576 + i*8 + o];
        }
        const float x0 = s_xv[0][i][tid];
        const float x1 = s_xv[1][i][tid];
        const float x2 = s_xv[2][i][tid];
#pragma unroll
        for (int o = 0; o < 8; ++o) {
            tv4[o][0] += x0*w4[o]; tv4[o][1] += x1*w4[o]; tv4[o][2] += x2*w4[o];
            tv5[o][0] += x0*w5[o]; tv5[o][1] += x1*w5[o]; tv5[o][2] += x2*w5[o];
        }
    }

    // Emit row: vbuf[pos][k] = sa * v[k]; exbuf[pos] = ex.
    float row[40];
    const float cs_out = 0.03608439182435161f;   // (1/sqrt32)*(1/sqrt24)
#pragma unroll
    for (int o = 0; o < 16; ++o)
        row[o] = sa * (shs*tv1[o] + tv2[o]) * cs_out;
#pragma unroll
    for (int o = 0; o < 8; ++o)
#pragma unroll
        for (int c = 0; c < 3; ++c) {
            const int c1 = (c+1) % 3, c2 = (c+2) % 3;
            const float vv = (tv3[o]*shv_[c] + shs*tv4[o][c]
                + (shv_[c2]*tv5[o][c1] - shv_[c1]*tv5[o][c2]) * 0.70710678118654752f)
                * 0.03125f;                      // (1/sqrt32)*(1/sqrt32)
            row[16 + o*3 + c] = sa * vv;
        }

    exbuf[pos] = ex;
    float4* vp = (float4*)(vbuf + (size_t)pos * 40);
#pragma unroll
    for (int t = 0; t < 10; ++t) {
        float4 v;
        v.x = row[4*t+0]; v.y = row[4*t+1]; v.z = row[4*t+2]; v.w = row[4*t+3];
        vp[t] = v;
    }
}

__global__ __launch_bounds__(256) void node_reduce(
    const int*   __restrict__ start,   // [N+1]
    const float* __restrict__ exbuf,   // [E]
    const float* __restrict__ vbuf,    // [E,40]
    float* __restrict__ out,           // [N,40]
    int N)
{
    const int wave = threadIdx.x >> 6;            // 4 waves/block
    const int lane = threadIdx.x & 63;
    const int n = blockIdx.x * 4 + wave;
    if (n >= N) return;

    const int r0 = start[n];
    const int r1 = start[n + 1];

    float z = 0.f, comp = 0.f;
    for (int r = r0; r < r1; ++r) {
        z += exbuf[r];                              // uniform addr -> broadcast
        if (lane < 40) comp += vbuf[(size_t)r * 40 + lane];
    }
    if (lane < 40)
        out[(size_t)n * 40 + lane] = (z > 0.f) ? comp * rsqrtf(z) : 0.f;
}

extern "C" void kernel_launch(void* const* d_in, const int* in_sizes, int n_in,
                              void* d_out, int out_size, void* d_ws, size_t ws_size,
                              hipStream_t stream) {
    const float* node_ft      = (const float*)d_in[0];
    const int*   edge_index   = (const int*)  d_in[1];
    const float* edge_sh      = (const float*)d_in[2];
    const float* edge_scalars = (const float*)d_in[3];
    const float* w_q_s        = (const float*)d_in[4];
    const float* w_q_v        = (const float*)d_in[5];
    const float* fck_w1       = (const float*)d_in[6];
    const float* fck_w2       = (const float*)d_in[7];
    const float* fcv_w1       = (const float*)d_in[8];
    const float* fcv_w2       = (const float*)d_in[9];
    const float* wdot_s       = (const float*)d_in[10];
    const float* wdot_v       = (const float*)d_in[11];

    const int N = in_sizes[0] / 40;   // node_ft [N, 40]
    const int E = in_sizes[2] / 4;    // edge_sh [E, 4]

    float* ws   = (float*)d_ws;
    float* qd   = ws;                               // N*20 floats
    int*   cnt  = (int*)(ws + (size_t)N * 20);      // N
    int*   start= cnt + N;                          // N+1
    int*   curs = start + N + 1;                    // N
    int*   flg  = curs + N;                         // 1
    size_t off  = (size_t)N * 20 + N + (N + 1) + N + 1;
    off = (off + 3) & ~(size_t)3;                   // 16B align for float4
    float* exbuf = ws + off;                        // E
    float* vbuf  = exbuf + E;                       // E*40 (E mult of 4 -> aligned)

    float* out = (float*)d_out;

    hipLaunchKernelGGL(node_pre, dim3((N + 255) / 256), dim3(256), 0, stream,
                       node_ft, edge_index, w_q_s, w_q_v, wdot_s, wdot_v,
                       qd, cnt, flg, N, E);
    hipLaunchKernelGGL(count_edges, dim3((E + 255) / 256), dim3(256), 0, stream,
                       edge_index, cnt, flg, E);
    hipLaunchKernelGGL(scan_kernel, dim3(1), dim3(1024), 0, stream,
                       cnt, start, curs, N);
    hipLaunchKernelGGL(edge_compute, dim3((E + BS - 1) / BS), dim3(BS), 0, stream,
                       node_ft, edge_index, edge_sh, edge_scalars,
                       fck_w1, fck_w2, fcv_w1, fcv_w2,
                       qd, curs, exbuf, vbuf, flg, N, E);
    hipLaunchKernelGGL(node_reduce, dim3((N + 3) / 4), dim3(256), 0, stream,
                       start, exbuf, vbuf, out, N);
}

// Round 4
// 345.997 us; speedup vs baseline: 2.1037x; 2.1037x over previous
//
#include <hip/hip_runtime.h>

// GraphAttention (e3nn-style) on MI355X — Round 4: LDS-staged weights.
// Round-3 lesson: the stall was never atomics — it was wave-uniform s_load
// weight delivery (120 KB/wave through a thrashed scalar L1 at ~200 cyc) with
// 10% occupancy. Fix: stage W2 slices in LDS per block, read via
// uniform-address ds_read_b128 broadcast. Split edge math into 3 kernels so
// each weight slice + bf16 value-columns fits in <=61 KB LDS (>=2 blocks/CU).
//
// Dims: M0=16 M1=8 Q0=8 Q1=4 O0=16 O1=8 EDGE_BASIS=16 HIDDEN=32
// TPK [32][320]: w1[0,128) w2[128,192) w3[192,256) w4[256,288) w5[288,320)
// TPV [32][640]: w1[0,256) w2[256,384) w3[384,512) w4[512,576) w5[576,640)
//
// Pipeline: node_pre | count_edges | scan | edge_k | edge_v_a | edge_v_b | node_reduce
// ws (4B units): qd[N*20] | cnt[N] | start[N+1] | cursor[N] | flag | pad |
//                exbuf[E] | sabuf[E] | posbuf[E] | vbuf[E*40]

#define BS 256

__device__ __forceinline__ float silu_f(float x) {
    return x * (1.0f / (1.0f + __expf(-x)));
}
__device__ __forceinline__ unsigned short f2b(float f) {   // f32 -> bf16 (RNE)
    unsigned u = __float_as_uint(f);
    u += 0x7fffu + ((u >> 16) & 1u);
    return (unsigned short)(u >> 16);
}
__device__ __forceinline__ float b2f(unsigned short h) {
    return __uint_as_float(((unsigned)h) << 16);
}

__global__ __launch_bounds__(256) void node_pre(
    const float* __restrict__ node_ft,
    const int*   __restrict__ ei,
    const float* __restrict__ w_q_s, const float* __restrict__ w_q_v,
    const float* __restrict__ wdot_s, const float* __restrict__ wdot_v,
    float* __restrict__ qd, int* __restrict__ cnt, int* __restrict__ flag,
    int N, int E)
{
    const int n = blockIdx.x * blockDim.x + threadIdx.x;
    if (n == 0) {
        int acc = 0;
        const int kmax = (E < 64) ? E : 64;
        for (int k = 0; k < kmax; ++k) acc |= ei[2*k + 1];
        *flag = (acc == 0) ? 1 : 0;   // int64 layout => odd words all zero
    }
    if (n >= N) return;
    cnt[n] = 0;

    const float* nf = node_ft + (size_t)n * 40;
    float xs[16];
#pragma unroll
    for (int i = 0; i < 16; ++i) xs[i] = nf[i];
    float q[8];
#pragma unroll
    for (int o = 0; o < 8; ++o) {
        float a = 0.f;
#pragma unroll
        for (int i = 0; i < 16; ++i) a += xs[i] * w_q_s[i*8 + o];
        q[o] = a * 0.25f;
    }
    float* qdn = qd + (size_t)n * 20;
#pragma unroll
    for (int j = 0; j < 8; ++j) {
        float a = 0.f;
#pragma unroll
        for (int i = 0; i < 8; ++i) a += q[i] * wdot_s[i*8 + j];
        qdn[j] = a;
    }
    float xv[8][3];
#pragma unroll
    for (int i = 0; i < 8; ++i)
#pragma unroll
        for (int c = 0; c < 3; ++c) xv[i][c] = nf[16 + i*3 + c];
    float qv[4][3];
#pragma unroll
    for (int o = 0; o < 4; ++o)
#pragma unroll
        for (int c = 0; c < 3; ++c) {
            float a = 0.f;
#pragma unroll
            for (int i = 0; i < 8; ++i) a += xv[i][c] * w_q_v[i*4 + o];
            qv[o][c] = a * 0.35355339059327379f;
        }
#pragma unroll
    for (int j = 0; j < 4; ++j)
#pragma unroll
        for (int c = 0; c < 3; ++c) {
            float a = 0.f;
#pragma unroll
            for (int i = 0; i < 4; ++i) a += qv[i][c] * wdot_v[i*4 + j];
            qdn[8 + j*3 + c] = a;
        }
}

__global__ __launch_bounds__(256) void count_edges(
    const int* __restrict__ ei, int* __restrict__ cnt,
    const int* __restrict__ flag, int E)
{
    const int e = blockIdx.x * blockDim.x + threadIdx.x;
    if (e >= E) return;
    const int is64 = *flag;
    const int rcv = is64 ? ei[2*(E + e)] : ei[E + e];
    atomicAdd(cnt + rcv, 1);
}

// 1 block, 1024 threads; shuffle-based scan (few barriers).
__global__ __launch_bounds__(1024) void scan_kernel(
    const int* __restrict__ cnt, int* __restrict__ start,
    int* __restrict__ cursor, int N)
{
    __shared__ int wsum[16];
    __shared__ int s_carry;
    const int tid = threadIdx.x, wave = tid >> 6, lane = tid & 63;
    if (tid == 0) s_carry = 0;
    __syncthreads();
    for (int base = 0; base < N; base += 1024) {
        const int i = base + tid;
        const int v = (i < N) ? cnt[i] : 0;
        int x = v;                                  // inclusive intra-wave scan
#pragma unroll
        for (int d = 1; d < 64; d <<= 1) {
            const int y = __shfl_up(x, d, 64);
            if (lane >= d) x += y;
        }
        if (lane == 63) wsum[wave] = x;
        __syncthreads();
        if (wave == 0 && lane < 16) {
            int w = wsum[lane];
#pragma unroll
            for (int d = 1; d < 16; d <<= 1) {
                const int y = __shfl_up(w, d, 64);
                if (lane >= d) w += y;              // lanes 16..63 inactive
            }
            wsum[lane] = w;                         // inclusive wave-prefix
        }
        __syncthreads();
        const int woff = (wave == 0) ? 0 : wsum[wave - 1];
        const int carry = s_carry;
        if (i < N) {
            const int s = carry + woff + x - v;     // exclusive
            start[i] = s;
            cursor[i] = s;
        }
        __syncthreads();
        if (tid == 0) s_carry = carry + wsum[15];
        __syncthreads();
    }
    if (tid == 0) start[N] = s_carry;
}

// ===================== edge_k: K-side TP + dot + softmax terms =====================
__global__ __launch_bounds__(BS) void edge_k(
    const float* __restrict__ node_ft,
    const int*   __restrict__ ei,
    const float* __restrict__ edge_sh,
    const float* __restrict__ edge_scalars,
    const float* __restrict__ fck_w1,       // [16,32] (stays global / s_load)
    const float* __restrict__ fck_w2,       // [32,320] -> LDS
    const float* __restrict__ qd,
    int*   __restrict__ cursor,
    float* __restrict__ exbuf,              // [E] CSR order
    float* __restrict__ sabuf,              // [E] edge order
    int*   __restrict__ posbuf,             // [E] edge order
    const int* __restrict__ flag,
    int N, int E)
{
    __shared__ float sW[32 * 320];                      // 40 KB
    __shared__ unsigned short s_xs[16][BS];             // 8 KB  (bf16 cols)
    __shared__ unsigned short s_xv[3][8][BS];           // 12 KB (bf16 cols)

    const int tid = threadIdx.x;
    for (int idx = tid; idx < 32 * 320; idx += BS) sW[idx] = fck_w2[idx];
    __syncthreads();

    const int e = blockIdx.x * BS + tid;
    if (e >= E) return;   // no barriers below

    const int is64 = *flag;
    const int snd = is64 ? ei[2*e]       : ei[e];
    const int rcv = is64 ? ei[2*(E + e)] : ei[E + e];

    const int pos = atomicAdd(cursor + rcv, 1);   // early: hide under FMAs

    const float4 sh4 = *(const float4*)(edge_sh + (size_t)e * 4);
    const float shs = sh4.x;
    const float shv0 = sh4.y, shv1 = sh4.z, shv2 = sh4.w;

    {
        const float4* nf4 = (const float4*)(node_ft + (size_t)snd * 40);
        float xb[40];
#pragma unroll
        for (int t = 0; t < 10; ++t) {
            const float4 v = nf4[t];
            xb[4*t+0] = v.x; xb[4*t+1] = v.y; xb[4*t+2] = v.z; xb[4*t+3] = v.w;
        }
#pragma unroll
        for (int i = 0; i < 16; ++i) s_xs[i][tid] = f2b(xb[i]);
#pragma unroll
        for (int i = 0; i < 8; ++i)
#pragma unroll
            for (int c = 0; c < 3; ++c) s_xv[c][i][tid] = f2b(xb[16 + i*3 + c]);
    }

    float es[16];
    {
        const float4* esp = (const float4*)(edge_scalars + (size_t)e * 16);
#pragma unroll
        for (int t = 0; t < 4; ++t) {
            const float4 v = esp[t];
            es[4*t+0] = v.x; es[4*t+1] = v.y; es[4*t+2] = v.z; es[4*t+3] = v.w;
        }
    }

    float hk[32];
#pragma unroll
    for (int j = 0; j < 32; ++j) {
        float a = 0.f;
#pragma unroll
        for (int t = 0; t < 16; ++t) a += es[t] * fck_w1[t*32 + j];
        hk[j] = silu_f(a * 0.25f);
    }

    // tk1 (xs path, o=8) + tk3 (xs->vec path, o=4): direct-t form
    float tk1[8] = {}, tk3[4] = {};
#pragma unroll 1
    for (int i = 0; i < 16; ++i) {
        const float xsi = b2f(s_xs[i][tid]);
#pragma unroll
        for (int j = 0; j < 32; ++j) {
            const float t = xsi * hk[j];
            const float4 a = *(const float4*)&sW[j*320 + i*8];
            const float4 b = *(const float4*)&sW[j*320 + i*8 + 4];
            const float4 c = *(const float4*)&sW[j*320 + 192 + i*4];
            tk1[0] += t*a.x; tk1[1] += t*a.y; tk1[2] += t*a.z; tk1[3] += t*a.w;
            tk1[4] += t*b.x; tk1[5] += t*b.y; tk1[6] += t*b.z; tk1[7] += t*b.w;
            tk3[0] += t*c.x; tk3[1] += t*c.y; tk3[2] += t*c.z; tk3[3] += t*c.w;
        }
    }

    // tk2 (vv-dot path)
    float tk2[8] = {};
#pragma unroll 1
    for (int i = 0; i < 8; ++i) {
        const float pv = (b2f(s_xv[0][i][tid])*shv0 + b2f(s_xv[1][i][tid])*shv1 +
                          b2f(s_xv[2][i][tid])*shv2) * 0.57735026918962576f;
#pragma unroll
        for (int j = 0; j < 32; ++j) {
            const float t = pv * hk[j];
            const float4 a = *(const float4*)&sW[j*320 + 128 + i*8];
            const float4 b = *(const float4*)&sW[j*320 + 128 + i*8 + 4];
            tk2[0] += t*a.x; tk2[1] += t*a.y; tk2[2] += t*a.z; tk2[3] += t*a.w;
            tk2[4] += t*b.x; tk2[5] += t*b.y; tk2[6] += t*b.z; tk2[7] += t*b.w;
        }
    }

    // tk4/tk5 (vec paths): j-first per i (weight shared over 3 components)
    float tk4[4][3] = {}, tk5[4][3] = {};
#pragma unroll 1
    for (int i = 0; i < 8; ++i) {
        float w4[4] = {}, w5[4] = {};
#pragma unroll
        for (int j = 0; j < 32; ++j) {
            const float hj = hk[j];
            const float4 a = *(const float4*)&sW[j*320 + 256 + i*4];
            const float4 b = *(const float4*)&sW[j*320 + 288 + i*4];
            w4[0] += hj*a.x; w4[1] += hj*a.y; w4[2] += hj*a.z; w4[3] += hj*a.w;
            w5[0] += hj*b.x; w5[1] += hj*b.y; w5[2] += hj*b.z; w5[3] += hj*b.w;
        }
        const float x0 = b2f(s_xv[0][i][tid]);
        const float x1 = b2f(s_xv[1][i][tid]);
        const float x2 = b2f(s_xv[2][i][tid]);
#pragma unroll
        for (int o = 0; o < 4; ++o) {
            tk4[o][0] += x0*w4[o]; tk4[o][1] += x1*w4[o]; tk4[o][2] += x2*w4[o];
            tk5[o][0] += x0*w5[o]; tk5[o][1] += x1*w5[o]; tk5[o][2] += x2*w5[o];
        }
    }

    float qdr[20];
    {
        const float4* qp = (const float4*)(qd + (size_t)rcv * 20);
#pragma unroll
        for (int t = 0; t < 5; ++t) {
            const float4 v = qp[t];
            qdr[4*t+0] = v.x; qdr[4*t+1] = v.y; qdr[4*t+2] = v.z; qdr[4*t+3] = v.w;
        }
    }
    float dots = 0.f, dotv = 0.f;
#pragma unroll
    for (int o = 0; o < 8; ++o) dots += qdr[o] * (shs*tk1[o] + tk2[o]);
    const float shv_[3] = {shv0, shv1, shv2};
#pragma unroll
    for (int o = 0; o < 4; ++o)
#pragma unroll
        for (int c = 0; c < 3; ++c) {
            const int c1 = (c+1) % 3, c2 = (c+2) % 3;
            const float kv = tk3[o]*shv_[c] + shs*tk4[o][c]
                + (shv_[c2]*tk5[o][c1] - shv_[c1]*tk5[o][c2]) * 0.70710678118654752f;
            dotv += qdr[8 + o*3 + c] * kv;
        }
    const float dot = dots * 4.0343567508008e-3f + dotv * 2.0171788261497e-3f;

    const float sa = __expf(0.5f * dot);
    exbuf[pos] = sa * sa;          // exp(dot)
    sabuf[e]   = sa;               // sqrt(exp(dot))
    posbuf[e]  = pos;
}

// ===================== edge_v_a: V scalar outputs (cols [0,384)) =====================
__global__ __launch_bounds__(BS) void edge_v_a(
    const float* __restrict__ node_ft,
    const int*   __restrict__ ei,
    const float* __restrict__ edge_sh,
    const float* __restrict__ edge_scalars,
    const float* __restrict__ fcv_w1,
    const float* __restrict__ fcv_w2,
    const float* __restrict__ sabuf,
    const int*   __restrict__ posbuf,
    float* __restrict__ vbuf,               // [E,40]
    const int* __restrict__ flag,
    int E)
{
    __shared__ float sW[32 * 384];                      // 48 KB
    __shared__ unsigned short s_xs[16][BS];             // 8 KB
    __shared__ unsigned short s_pv[8][BS];              // 4 KB

    const int tid = threadIdx.x;
#pragma unroll 1
    for (int j = 0; j < 32; ++j)
        for (int c = tid; c < 384; c += BS) sW[j*384 + c] = fcv_w2[j*640 + c];
    __syncthreads();

    const int e = blockIdx.x * BS + tid;
    if (e >= E) return;

    const int is64 = *flag;
    const int snd = is64 ? ei[2*e] : ei[e];

    const float4 sh4 = *(const float4*)(edge_sh + (size_t)e * 4);
    const float shs = sh4.x;

    {
        const float4* nf4 = (const float4*)(node_ft + (size_t)snd * 40);
        float xb[40];
#pragma unroll
        for (int t = 0; t < 10; ++t) {
            const float4 v = nf4[t];
            xb[4*t+0] = v.x; xb[4*t+1] = v.y; xb[4*t+2] = v.z; xb[4*t+3] = v.w;
        }
#pragma unroll
        for (int i = 0; i < 16; ++i) s_xs[i][tid] = f2b(xb[i]);
#pragma unroll
        for (int i = 0; i < 8; ++i) {
            const float pv = (xb[16+i*3]*sh4.y + xb[17+i*3]*sh4.z + xb[18+i*3]*sh4.w)
                             * 0.57735026918962576f;
            s_pv[i][tid] = f2b(pv);
        }
    }

    float es[16];
    {
        const float4* esp = (const float4*)(edge_scalars + (size_t)e * 16);
#pragma unroll
        for (int t = 0; t < 4; ++t) {
            const float4 v = esp[t];
            es[4*t+0] = v.x; es[4*t+1] = v.y; es[4*t+2] = v.z; es[4*t+3] = v.w;
        }
    }
    float hv[32];
#pragma unroll
    for (int j = 0; j < 32; ++j) {
        float a = 0.f;
#pragma unroll
        for (int t = 0; t < 16; ++t) a += es[t] * fcv_w1[t*32 + j];
        hv[j] = silu_f(a * 0.25f);
    }

    float tv1[16] = {};
#pragma unroll 1
    for (int i = 0; i < 16; ++i) {
        const float xsi = b2f(s_xs[i][tid]);
#pragma unroll
        for (int j = 0; j < 32; ++j) {
            const float t = xsi * hv[j];
            const float4 a = *(const float4*)&sW[j*384 + i*16];
            const float4 b = *(const float4*)&sW[j*384 + i*16 + 4];
            const float4 c = *(const float4*)&sW[j*384 + i*16 + 8];
            const float4 d = *(const float4*)&sW[j*384 + i*16 + 12];
            tv1[0]  += t*a.x; tv1[1]  += t*a.y; tv1[2]  += t*a.z; tv1[3]  += t*a.w;
            tv1[4]  += t*b.x; tv1[5]  += t*b.y; tv1[6]  += t*b.z; tv1[7]  += t*b.w;
            tv1[8]  += t*c.x; tv1[9]  += t*c.y; tv1[10] += t*c.z; tv1[11] += t*c.w;
            tv1[12] += t*d.x; tv1[13] += t*d.y; tv1[14] += t*d.z; tv1[15] += t*d.w;
        }
    }
    float tv2[16] = {};
#pragma unroll 1
    for (int i = 0; i < 8; ++i) {
        const float pv = b2f(s_pv[i][tid]);
#pragma unroll
        for (int j = 0; j < 32; ++j) {
            const float t = pv * hv[j];
            const float4 a = *(const float4*)&sW[j*384 + 256 + i*16];
            const float4 b = *(const float4*)&sW[j*384 + 256 + i*16 + 4];
            const float4 c = *(const float4*)&sW[j*384 + 256 + i*16 + 8];
            const float4 d = *(const float4*)&sW[j*384 + 256 + i*16 + 12];
            tv2[0]  += t*a.x; tv2[1]  += t*a.y; tv2[2]  += t*a.z; tv2[3]  += t*a.w;
            tv2[4]  += t*b.x; tv2[5]  += t*b.y; tv2[6]  += t*b.z; tv2[7]  += t*b.w;
            tv2[8]  += t*c.x; tv2[9]  += t*c.y; tv2[10] += t*c.z; tv2[11] += t*c.w;
            tv2[12] += t*d.x; tv2[13] += t*d.y; tv2[14] += t*d.z; tv2[15] += t*d.w;
        }
    }

    const float sa = sabuf[e];
    const int pos = posbuf[e];
    const float cs_out = 0.03608439182435161f;   // (1/sqrt32)*(1/sqrt24)
    float4* vp = (float4*)(vbuf + (size_t)pos * 40);
#pragma unroll
    for (int t = 0; t < 4; ++t) {
        float4 r;
        r.x = sa * (shs*tv1[4*t+0] + tv2[4*t+0]) * cs_out;
        r.y = sa * (shs*tv1[4*t+1] + tv2[4*t+1]) * cs_out;
        r.z = sa * (shs*tv1[4*t+2] + tv2[4*t+2]) * cs_out;
        r.w = sa * (shs*tv1[4*t+3] + tv2[4*t+3]) * cs_out;
        vp[t] = r;
    }
}

// ===================== edge_v_b: V vector outputs (cols [384,640)) =====================
__global__ __launch_bounds__(BS) void edge_v_b(
    const float* __restrict__ node_ft,
    const int*   __restrict__ ei,
    const float* __restrict__ edge_sh,
    const float* __restrict__ edge_scalars,
    const float* __restrict__ fcv_w1,
    const float* __restrict__ fcv_w2,
    const float* __restrict__ sabuf,
    const int*   __restrict__ posbuf,
    float* __restrict__ vbuf,               // [E,40]
    const int* __restrict__ flag,
    int E)
{
    __shared__ float sW[32 * 256];                      // 32 KB (local col = global-384)
    __shared__ unsigned short s_xs[16][BS];             // 8 KB
    __shared__ unsigned short s_xv[3][8][BS];           // 12 KB

    const int tid = threadIdx.x;
#pragma unroll 1
    for (int j = 0; j < 32; ++j)
        for (int c = tid; c < 256; c += BS) sW[j*256 + c] = fcv_w2[j*640 + 384 + c];
    __syncthreads();

    const int e = blockIdx.x * BS + tid;
    if (e >= E) return;

    const int is64 = *flag;
    const int snd = is64 ? ei[2*e] : ei[e];

    const float4 sh4 = *(const float4*)(edge_sh + (size_t)e * 4);
    const float shs = sh4.x;
    const float shv_[3] = {sh4.y, sh4.z, sh4.w};

    {
        const float4* nf4 = (const float4*)(node_ft + (size_t)snd * 40);
        float xb[40];
#pragma unroll
        for (int t = 0; t < 10; ++t) {
            const float4 v = nf4[t];
            xb[4*t+0] = v.x; xb[4*t+1] = v.y; xb[4*t+2] = v.z; xb[4*t+3] = v.w;
        }
#pragma unroll
        for (int i = 0; i < 16; ++i) s_xs[i][tid] = f2b(xb[i]);
#pragma unroll
        for (int i = 0; i < 8; ++i)
#pragma unroll
            for (int c = 0; c < 3; ++c) s_xv[c][i][tid] = f2b(xb[16 + i*3 + c]);
    }

    float es[16];
    {
        const float4* esp = (const float4*)(edge_scalars + (size_t)e * 16);
#pragma unroll
        for (int t = 0; t < 4; ++t) {
            const float4 v = esp[t];
            es[4*t+0] = v.x; es[4*t+1] = v.y; es[4*t+2] = v.z; es[4*t+3] = v.w;
        }
    }
    float hv[32];
#pragma unroll
    for (int j = 0; j < 32; ++j) {
        float a = 0.f;
#pragma unroll
        for (int t = 0; t < 16; ++t) a += es[t] * fcv_w1[t*32 + j];
        hv[j] = silu_f(a * 0.25f);
    }

    // tv3 (xs (x) shv path): scalar accumulation, shv applied in epilogue
    float tv3[8] = {};
#pragma unroll 1
    for (int i = 0; i < 16; ++i) {
        const float xsi = b2f(s_xs[i][tid]);
#pragma unroll
        for (int j = 0; j < 32; ++j) {
            const float t = xsi * hv[j];
            const float4 a = *(const float4*)&sW[j*256 + i*8];
            const float4 b = *(const float4*)&sW[j*256 + i*8 + 4];
            tv3[0] += t*a.x; tv3[1] += t*a.y; tv3[2] += t*a.z; tv3[3] += t*a.w;
            tv3[4] += t*b.x; tv3[5] += t*b.y; tv3[6] += t*b.z; tv3[7] += t*b.w;
        }
    }

    float tv4[8][3] = {}, tv5[8][3] = {};
#pragma unroll 1
    for (int i = 0; i < 8; ++i) {
        float w4[8] = {}, w5[8] = {};
#pragma unroll
        for (int j = 0; j < 32; ++j) {
            const float hj = hv[j];
            const float4 a = *(const float4*)&sW[j*256 + 128 + i*8];
            const float4 b = *(const float4*)&sW[j*256 + 128 + i*8 + 4];
            const float4 c = *(const float4*)&sW[j*256 + 192 + i*8];
            const float4 d = *(const float4*)&sW[j*256 + 192 + i*8 + 4];
            w4[0] += hj*a.x; w4[1] += hj*a.y; w4[2] += hj*a.z; w4[3] += hj*a.w;
            w4[4] += hj*b.x; w4[5] += hj*b.y; w4[6] += hj*b.z; w4[7] += hj*b.w;
            w5[0] += hj*c.x; w5[1] += hj*c.y; w5[2] += hj*c.z; w5[3] += hj*c.w;
            w5[4] += hj*d.x; w5[5] += hj*d.y; w5[6] += hj*d.z; w5[7] += hj*d.w;
        }
        const float x0 = b2f(s_xv[0][i][tid]);
        const float x1 = b2f(s_xv[1][i][tid]);
        const float x2 = b2f(s_xv[2][i][tid]);
#pragma unroll
        for (int o = 0; o < 8; ++o) {
            tv4[o][0] += x0*w4[o]; tv4[o][1] += x1*w4[o]; tv4[o][2] += x2*w4[o];
            tv5[o][0] += x0*w5[o]; tv5[o][1] += x1*w5[o]; tv5[o][2] += x2*w5[o];
        }
    }

    const float sa = sabuf[e];
    const int pos = posbuf[e];
    float row[24];
#pragma unroll
    for (int o = 0; o < 8; ++o)
#pragma unroll
        for (int c = 0; c < 3; ++c) {
            const int c1 = (c+1) % 3, c2 = (c+2) % 3;
            const float vv = (tv3[o]*shv_[c] + shs*tv4[o][c]
                + (shv_[c2]*tv5[o][c1] - shv_[c1]*tv5[o][c2]) * 0.70710678118654752f)
                * 0.03125f;                      // (1/sqrt32)*(1/sqrt32)
            row[o*3 + c] = sa * vv;
        }
    float4* vp = (float4*)(vbuf + (size_t)pos * 40 + 16);
#pragma unroll
    for (int t = 0; t < 6; ++t) {
        float4 r;
        r.x = row[4*t+0]; r.y = row[4*t+1]; r.z = row[4*t+2]; r.w = row[4*t+3];
        vp[t] = r;
    }
}

__global__ __launch_bounds__(256) void node_reduce(
    const int*   __restrict__ start,
    const float* __restrict__ exbuf,
    const float* __restrict__ vbuf,
    float* __restrict__ out, int N)
{
    const int wave = threadIdx.x >> 6;
    const int lane = threadIdx.x & 63;
    const int n = blockIdx.x * 4 + wave;
    if (n >= N) return;
    const int r0 = start[n], r1 = start[n + 1];
    float z = 0.f, comp = 0.f;
    for (int r = r0; r < r1; ++r) {
        z += exbuf[r];
        if (lane < 40) comp += vbuf[(size_t)r * 40 + lane];
    }
    if (lane < 40)
        out[(size_t)n * 40 + lane] = (z > 0.f) ? comp * rsqrtf(z) : 0.f;
}

extern "C" void kernel_launch(void* const* d_in, const int* in_sizes, int n_in,
                              void* d_out, int out_size, void* d_ws, size_t ws_size,
                              hipStream_t stream) {
    const float* node_ft      = (const float*)d_in[0];
    const int*   edge_index   = (const int*)  d_in[1];
    const float* edge_sh      = (const float*)d_in[2];
    const float* edge_scalars = (const float*)d_in[3];
    const float* w_q_s        = (const float*)d_in[4];
    const float* w_q_v        = (const float*)d_in[5];
    const float* fck_w1       = (const float*)d_in[6];
    const float* fck_w2       = (const float*)d_in[7];
    const float* fcv_w1       = (const float*)d_in[8];
    const float* fcv_w2       = (const float*)d_in[9];
    const float* wdot_s       = (const float*)d_in[10];
    const float* wdot_v       = (const float*)d_in[11];

    const int N = in_sizes[0] / 40;
    const int E = in_sizes[2] / 4;

    float* ws    = (float*)d_ws;
    float* qd    = ws;                               // N*20
    int*   cnt   = (int*)(ws + (size_t)N * 20);      // N
    int*   start = cnt + N;                          // N+1
    int*   curs  = start + N + 1;                    // N
    int*   flg   = curs + N;                         // 1
    size_t off   = (size_t)N * 20 + N + (N + 1) + N + 1;
    off = (off + 3) & ~(size_t)3;                    // 16B align
    float* exbuf  = ws + off;                        // E
    float* sabuf  = exbuf + E;                       // E
    int*   posbuf = (int*)(sabuf + E);               // E
    float* vbuf   = (float*)(posbuf + E);            // E*40 (E%4==0 -> aligned)

    float* out = (float*)d_out;

    hipLaunchKernelGGL(node_pre, dim3((N + 255) / 256), dim3(256), 0, stream,
                       node_ft, edge_index, w_q_s, w_q_v, wdot_s, wdot_v,
                       qd, cnt, flg, N, E);
    hipLaunchKernelGGL(count_edges, dim3((E + 255) / 256), dim3(256), 0, stream,
                       edge_index, cnt, flg, E);
    hipLaunchKernelGGL(scan_kernel, dim3(1), dim3(1024), 0, stream,
                       cnt, start, curs, N);
    hipLaunchKernelGGL(edge_k, dim3((E + BS - 1) / BS), dim3(BS), 0, stream,
                       node_ft, edge_index, edge_sh, edge_scalars,
                       fck_w1, fck_w2, qd, curs, exbuf, sabuf, posbuf, flg, N, E);
    hipLaunchKernelGGL(edge_v_a, dim3((E + BS - 1) / BS), dim3(BS), 0, stream,
                       node_ft, edge_index, edge_sh, edge_scalars,
                       fcv_w1, fcv_w2, sabuf, posbuf, vbuf, flg, E);
    hipLaunchKernelGGL(edge_v_b, dim3((E + BS - 1) / BS), dim3(BS), 0, stream,
                       node_ft, edge_index, edge_sh, edge_scalars,
                       fcv_w1, fcv_w2, sabuf, posbuf, vbuf, flg, E);
    hipLaunchKernelGGL(node_reduce, dim3((N + 3) / 4), dim3(256), 0, stream,
                       start, exbuf, vbuf, out, N);
}